// Round 15
// baseline (67.740 us; speedup 1.0000x reference)
//
#include <hip/hip_runtime.h>
#include <stdint.h>

// VQ codebook assignment via split-precision bf16 MFMA:
//   argmin_k ||z-c_k||^2 == argmin_k (csq[k] - 2 z.c_k)
//   z.c ~= z_hi.c_hi + z_lo.c_hi + z_hi.c_lo   (bf16 hi/lo split, K_eff=768)
// Round-15: r14 + wave-staggered ct order (ct = (ctl + w&3) & 3) to break
// wave phase-lock: waves hit their load-wait windows at different offsets so
// the CU's MFMA pipe stays fed. Fold-order changes are safe: all ties /
// sub-TAU margins route to order-independent exact fp64 paths (top-2 compare
// or full re-solve), lowest-index tie-break preserved.

#define NQ 32768
#define ND 256
#define NK 1024
#define TAU 0.004f

typedef short bf16x8 __attribute__((ext_vector_type(8)));
typedef float f32x4  __attribute__((ext_vector_type(4)));

// ws layout (bytes); ~1.06 MB
// cbw: ushort [64 koct][1024 codes][8]; koct 0..31 = c_hi octet, 32..63 = c_lo
#define WS_CBW 0
#define WS_CSQ (64 * 1024 * 8 * 2)       // 1 MB; then double csq[1024]
#define WS_NEEDED (WS_CSQ + 1024 * 8)

__device__ __forceinline__ ushort bf_trunc(float x) {
    return (ushort)(__builtin_bit_cast(uint32_t, x) >> 16);
}
__device__ __forceinline__ float bf_back(ushort h) {
    return __builtin_bit_cast(float, ((uint32_t)h) << 16);
}

// ---------------------------------------------------------------- prep ----
__global__ __launch_bounds__(256)
void vq_prep(const float* __restrict__ cb, uint8_t* __restrict__ ws)
{
    ushort* cbw = (ushort*)(ws + WS_CBW);
    double* csq = (double*)(ws + WS_CSQ);

    const int tid  = threadIdx.x;
    const int code = blockIdx.x * 4 + (tid >> 6);
    const int lane = tid & 63;

    const int d0 = lane * 4;
    const float4 v = *reinterpret_cast<const float4*>(&cb[(size_t)code * ND + d0]);
    const float xs[4] = {v.x, v.y, v.z, v.w};

    ushort4 h4, l4;
    ushort* hp = &h4.x; ushort* lp = &l4.x;
    double ss = 0.0;
    #pragma unroll
    for (int j = 0; j < 4; ++j) {
        const ushort h = bf_trunc(xs[j]);
        hp[j] = h;
        lp[j] = bf_trunc(xs[j] - bf_back(h));
        ss += (double)xs[j] * (double)xs[j];
    }

    const int oct = d0 >> 3;             // 0..31
    const int off = d0 & 7;              // 0 or 4
    *reinterpret_cast<ushort4*>(&cbw[((size_t)oct * NK + code) * 8 + off]) = h4;
    *reinterpret_cast<ushort4*>(&cbw[((size_t)(32 + oct) * NK + code) * 8 + off]) = l4;

    #pragma unroll
    for (int m = 1; m < 64; m <<= 1) ss += __shfl_xor(ss, m);
    if (lane == 0) csq[code] = ss;
}

// branchless merge of two (b1,b2,b3,i1,i2) top-3 candidate sets
__device__ __forceinline__ void merge5(float& B1, float& B2, float& B3,
                                       int& I1, int& I2,
                                       float o1, float o2, float o3,
                                       int oi1, int oi2)
{
    const bool aw = (B1 < o1) || (B1 == o1 && I1 < oi1);
    const float n1 = aw ? B1 : o1;  const int ni1 = aw ? I1 : oi1;
    const float c1 = aw ? o1 : B1;  const int ci1 = aw ? oi1 : I1;  // loser 1st
    const float c2 = aw ? B2 : o2;  const int ci2 = aw ? I2 : oi2;  // winner 2nd
    const bool sw = (c2 < c1) || (c2 == c1 && ci2 < ci1);
    const float n2 = sw ? c2 : c1;  const int ni2 = sw ? ci2 : ci1;
    const float n3 = fminf(sw ? c1 : c2,
                           fminf(aw ? B3 : o3, aw ? o2 : B2));
    B1 = n1; I1 = ni1; B2 = n2; I2 = ni2; B3 = n3;
}

// ---------------------------------------------------------------- main ----
// 512 threads = 8 waves; block = 64 queries x 1024 codes (4 code-tiles).
__global__ __launch_bounds__(512, 4)
void vq_main(const float* __restrict__ z, const float* __restrict__ cb,
             uint8_t* __restrict__ ws, float* __restrict__ out)
{
    __shared__ alignas(16) ushort zt[64][512];  // z hi|lo, XOR-swizzled (64KB)
    __shared__ float  csq_l[NK];
    __shared__ int    nf;

    // scratch carved from zt AFTER all MFMA reads (barrier-protected):
    float*  wb1f = reinterpret_cast<float*>(&zt[0][0]);   // [8][64] rows 0-1
    float*  wb2f = reinterpret_cast<float*>(&zt[2][0]);
    float*  wb3f = reinterpret_cast<float*>(&zt[4][0]);
    int*    wbi1 = reinterpret_cast<int*>(&zt[6][0]);
    int*    wbi2 = reinterpret_cast<int*>(&zt[8][0]);
    int*    qidx = reinterpret_cast<int*>(&zt[10][0]);    // 64 ints
    int*    qf   = reinterpret_cast<int*>(&zt[11][0]);    // 64 ints
    float*  marg = reinterpret_cast<float*>(&zt[12][0]);  // 64 f32
    int*    mI1  = reinterpret_cast<int*>(&zt[13][0]);    // 64 ints
    int*    mI2  = reinterpret_cast<int*>(&zt[14][0]);    // 64 ints
    float*  zrow = reinterpret_cast<float*>(&zt[16][0]);  // 256 f32
    double* red  = reinterpret_cast<double*>(&zt[20][0]); // 512 f64 rows 20-23
    int*    redi = reinterpret_cast<int*>(&zt[26][0]);    // 512 int rows 26-27

    const ushort* cbw  = (const ushort*)(ws + WS_CBW);
    const double* csqd = (const double*)(ws + WS_CSQ);

    const int tid  = threadIdx.x;
    const int lane = tid & 63;
    const int w    = tid >> 6;            // wave 0..7
    const int cl   = lane & 15;
    const int g    = lane >> 4;           // quarter 0..3
    const int q0   = blockIdx.x * 64;

    if (tid == 0) nf = 0;

    // --- stage z tile: 64q x 256d fp32 -> hi/lo bf16, swizzled 16B units
    {
        const int rr = tid >> 6;
        const int c4 = (tid & 63) * 4;
        const int uh = c4 >> 3;
        const int ul = (256 + c4) >> 3;
        #pragma unroll
        for (int it = 0; it < 8; ++it) {
            const int q = it * 8 + rr;
            const float4 v = *reinterpret_cast<const float4*>(
                &z[(size_t)(q0 + q) * ND + c4]);
            const float xs[4] = {v.x, v.y, v.z, v.w};
            ushort4 h4, l4;
            ushort* hp = &h4.x; ushort* lp = &l4.x;
            #pragma unroll
            for (int j = 0; j < 4; ++j) {
                const ushort h = bf_trunc(xs[j]);
                hp[j] = h;
                lp[j] = bf_trunc(xs[j] - bf_back(h));
            }
            const int sw = q & 7;
            *reinterpret_cast<ushort4*>(&zt[q][((uh ^ sw) << 3) + (c4 & 7)]) = h4;
            *reinterpret_cast<ushort4*>(&zt[q][((ul ^ sw) << 3) + (c4 & 7)]) = l4;
        }
    }
    #pragma unroll
    for (int i = 0; i < 2; ++i)
        csq_l[i * 512 + tid] = (float)csqd[i * 512 + tid];
    __syncthreads();

    // per-lane running top-3 (values) + top-2 (indices), per q-tile slot
    float b1[4], b2[4], b3[4]; int i1[4], i2[4];
    #pragma unroll
    for (int s = 0; s < 4; ++s) {
        b1[s] = 3.0e38f; b2[s] = 3.0e38f; b3[s] = 3.0e38f; i1[s] = 0; i2[s] = 0;
    }

    #pragma unroll 1
    for (int ctl = 0; ctl < 4; ++ctl) {
        const int ct = (ctl + (w & 3)) & 3;   // wave-staggered tile order
        f32x4 acc[2][4];                  // [cm][qt]
        #pragma unroll
        for (int cm = 0; cm < 2; ++cm)
            #pragma unroll
            for (int qt = 0; qt < 4; ++qt)
                acc[cm][qt] = (f32x4){0.f, 0.f, 0.f, 0.f};

        const int cbase = ct * 256 + w * 32;

        #pragma unroll 1
        for (int kk = 0; kk < 8; ++kk) {
            bf16x8 cfh[2], cfl[2];
            #pragma unroll
            for (int cm = 0; cm < 2; ++cm) {
                const int code = cbase + cm * 16 + cl;
                const int oh   = kk * 4 + g;
                cfh[cm] = *reinterpret_cast<const bf16x8*>(
                    &cbw[((size_t)oh * NK + code) * 8]);
                cfl[cm] = *reinterpret_cast<const bf16x8*>(
                    &cbw[((size_t)(32 + oh) * NK + code) * 8]);
            }
            bf16x8 zfh[4], zfl[4];
            #pragma unroll
            for (int qt = 0; qt < 4; ++qt) {
                const int q  = qt * 16 + cl;
                const int uh = (kk * 4 + g) ^ (q & 7);
                const int ul = (32 + kk * 4 + g) ^ (q & 7);
                zfh[qt] = *reinterpret_cast<const bf16x8*>(&zt[q][uh << 3]);
                zfl[qt] = *reinterpret_cast<const bf16x8*>(&zt[q][ul << 3]);
            }
            #pragma unroll
            for (int cm = 0; cm < 2; ++cm)
                #pragma unroll
                for (int qt = 0; qt < 4; ++qt) {
                    acc[cm][qt] = __builtin_amdgcn_mfma_f32_16x16x32_bf16(
                        cfh[cm], zfh[qt], acc[cm][qt], 0, 0, 0);
                    acc[cm][qt] = __builtin_amdgcn_mfma_f32_16x16x32_bf16(
                        cfh[cm], zfl[qt], acc[cm][qt], 0, 0, 0);
                    acc[cm][qt] = __builtin_amdgcn_mfma_f32_16x16x32_bf16(
                        cfl[cm], zfh[qt], acc[cm][qt], 0, 0, 0);
                }
        }

        // branchless top-3 fold (fixup net makes fold order safe)
        #pragma unroll
        for (int cm = 0; cm < 2; ++cm) {
            const int kb = cbase + cm * 16 + g * 4;
            const float4 cs4 = *reinterpret_cast<const float4*>(&csq_l[kb]);
            const float css[4] = {cs4.x, cs4.y, cs4.z, cs4.w};
            #pragma unroll
            for (int qt = 0; qt < 4; ++qt)
                #pragma unroll
                for (int r = 0; r < 4; ++r) {
                    const float d = fmaf(-2.0f, acc[cm][qt][r], css[r]);
                    const int k = kb + r;
                    const bool lt1 = d < b1[qt];
                    const bool lt2 = d < b2[qt];
                    i2[qt] = lt1 ? i1[qt] : (lt2 ? k : i2[qt]);
                    i1[qt] = lt1 ? k : i1[qt];
                    b3[qt] = fminf(b3[qt], fmaxf(b2[qt], d));   // uses old b2
                    b2[qt] = fminf(fmaxf(b1[qt], d), b2[qt]);   // med3(b1,b2,d)
                    b1[qt] = fminf(b1[qt], d);
                }
        }
    }

    __syncthreads();   // all waves done reading zt -> safe to carve scratch

    // --- combine the 4 quarters (same q = qt*16+cl, different codes)
    #pragma unroll
    for (int qt = 0; qt < 4; ++qt) {
        float B1 = b1[qt], B2 = b2[qt], B3 = b3[qt];
        int   I1 = i1[qt], I2 = i2[qt];
        #pragma unroll
        for (int m = 16; m < 64; m <<= 1) {
            const float o1 = __shfl_xor(B1, m);
            const float o2 = __shfl_xor(B2, m);
            const float o3 = __shfl_xor(B3, m);
            const int  oi1 = __shfl_xor(I1, m);
            const int  oi2 = __shfl_xor(I2, m);
            merge5(B1, B2, B3, I1, I2, o1, o2, o3, oi1, oi2);
        }
        if (g == 0) {
            const int q = qt * 16 + cl;
            wb1f[w * 64 + q] = B1; wb2f[w * 64 + q] = B2; wb3f[w * 64 + q] = B3;
            wbi1[w * 64 + q] = I1; wbi2[w * 64 + q] = I2;
        }
    }
    __syncthreads();

    // --- combine 8 wave candidates (tid<64 owns query tid)
    if (tid < 64) {
        float B1 = wb1f[tid], B2 = wb2f[tid], B3 = wb3f[tid];
        int   I1 = wbi1[tid], I2 = wbi2[tid];
        #pragma unroll
        for (int ww = 1; ww < 8; ++ww)
            merge5(B1, B2, B3, I1, I2,
                   wb1f[ww * 64 + tid], wb2f[ww * 64 + tid],
                   wb3f[ww * 64 + tid], wbi1[ww * 64 + tid],
                   wbi2[ww * 64 + tid]);
        qidx[tid] = I1;
        marg[tid] = B2 - B1;
        mI1[tid]  = I1;
        mI2[tid]  = I2;
        if (B3 - B1 < TAU) {           // 3 candidates within TAU: full resolve
            const int pos = atomicAdd(&nf, 1);
            qf[pos] = tid;
        }
    }
    __syncthreads();

    // --- parallel O(1) fixup: wave w handles queries w*8..w*8+7.
    #pragma unroll 1
    for (int j = 0; j < 8; ++j) {
        const int i = w * 8 + j;
        if (marg[i] >= TAU) continue;          // wave-uniform skip
        const int I1 = mI1[i], I2 = mI2[i];
        const int row = (lane < 32) ? I1 : I2;
        const int d0 = (lane & 31) * 8;
        const float* zr = &z[(size_t)(q0 + i) * ND + d0];
        const float* cr = &cb[(size_t)row * ND + d0];
        const float4 za = *reinterpret_cast<const float4*>(zr);
        const float4 zb = *reinterpret_cast<const float4*>(zr + 4);
        const float4 ca = *reinterpret_cast<const float4*>(cr);
        const float4 cb4 = *reinterpret_cast<const float4*>(cr + 4);
        double s = 0.0, t;
        t = (double)za.x - ca.x;  s = fma(t, t, s);
        t = (double)za.y - ca.y;  s = fma(t, t, s);
        t = (double)za.z - ca.z;  s = fma(t, t, s);
        t = (double)za.w - ca.w;  s = fma(t, t, s);
        t = (double)zb.x - cb4.x; s = fma(t, t, s);
        t = (double)zb.y - cb4.y; s = fma(t, t, s);
        t = (double)zb.z - cb4.z; s = fma(t, t, s);
        t = (double)zb.w - cb4.w; s = fma(t, t, s);
        #pragma unroll
        for (int m = 1; m < 32; m <<= 1) s += __shfl_xor(s, m);
        const double o = __shfl_xor(s, 32);
        if (lane == 0) {
            const double e1 = s, e2 = o;
            if ((e2 < e1) || (e2 == e1 && I2 < I1)) qidx[i] = I2;
        }
    }
    __syncthreads();

    // --- rare full fp64 re-solve (3 candidates within TAU); updates qidx
    const int nfl = nf;
    #pragma unroll 1
    for (int i = 0; i < nfl; ++i) {
        const int ql = qf[i];
        if (tid < 64)
            *reinterpret_cast<float4*>(&zrow[tid * 4]) =
                *reinterpret_cast<const float4*>(
                    &z[(size_t)(q0 + ql) * ND + tid * 4]);
        __syncthreads();

        double best = 1.0e300; int bi = 0;
        #pragma unroll 1
        for (int j = 0; j < 2; ++j) {
            const int k = tid * 2 + j;
            const float* row = &cb[(size_t)k * ND];
            double sa = 0.0, sb = 0.0, sc = 0.0, sd = 0.0;
            #pragma unroll 4
            for (int d = 0; d < ND; d += 16) {
                const float4 c0 = *reinterpret_cast<const float4*>(&row[d]);
                const float4 c1 = *reinterpret_cast<const float4*>(&row[d + 4]);
                const float4 c2 = *reinterpret_cast<const float4*>(&row[d + 8]);
                const float4 c3 = *reinterpret_cast<const float4*>(&row[d + 12]);
                double t;
                t = (double)zrow[d]      - c0.x; sa = fma(t, t, sa);
                t = (double)zrow[d + 1]  - c0.y; sa = fma(t, t, sa);
                t = (double)zrow[d + 2]  - c0.z; sa = fma(t, t, sa);
                t = (double)zrow[d + 3]  - c0.w; sa = fma(t, t, sa);
                t = (double)zrow[d + 4]  - c1.x; sb = fma(t, t, sb);
                t = (double)zrow[d + 5]  - c1.y; sb = fma(t, t, sb);
                t = (double)zrow[d + 6]  - c1.z; sb = fma(t, t, sb);
                t = (double)zrow[d + 7]  - c1.w; sb = fma(t, t, sb);
                t = (double)zrow[d + 8]  - c2.x; sc = fma(t, t, sc);
                t = (double)zrow[d + 9]  - c2.y; sc = fma(t, t, sc);
                t = (double)zrow[d + 10] - c2.z; sc = fma(t, t, sc);
                t = (double)zrow[d + 11] - c2.w; sc = fma(t, t, sc);
                t = (double)zrow[d + 12] - c3.x; sd = fma(t, t, sd);
                t = (double)zrow[d + 13] - c3.y; sd = fma(t, t, sd);
                t = (double)zrow[d + 14] - c3.z; sd = fma(t, t, sd);
                t = (double)zrow[d + 15] - c3.w; sd = fma(t, t, sd);
            }
            const double s = (sa + sb) + (sc + sd);
            if (s < best) { best = s; bi = k; }
        }
        red[tid] = best; redi[tid] = bi;
        __syncthreads();
        #pragma unroll 1
        for (int m = 256; m > 0; m >>= 1) {
            if (tid < m) {
                if (red[tid + m] < red[tid] ||
                    (red[tid + m] == red[tid] && redi[tid + m] < redi[tid])) {
                    red[tid] = red[tid + m]; redi[tid] = redi[tid + m];
                }
            }
            __syncthreads();
        }
        if (tid == 0) qidx[ql] = redi[0];
        __syncthreads();
    }

    // --- single unconditional gather: out[q][:] = cb[qidx[q]][:]
    {
        const int rr = tid >> 6;
        const int c  = (tid & 63) * 4;
        #pragma unroll
        for (int it = 0; it < 8; ++it) {
            const int q = it * 8 + rr;
            const int k = qidx[q];
            *reinterpret_cast<float4*>(&out[(size_t)(q0 + q) * ND + c]) =
                *reinterpret_cast<const float4*>(&cb[(size_t)k * ND + c]);
        }
    }
}

// ------------------------------------------------- fallback (round-1) -----
__global__ __launch_bounds__(256, 2)
void vq_fallback(const float* __restrict__ z, const float* __restrict__ cb,
                 float* __restrict__ out)
{
    __shared__ float z_t[ND][64];
    __shared__ float cb_t[32][64];
    __shared__ float csq[NK];
    __shared__ int   idx_lds[64];

    const int tid = threadIdx.x;
    const int tx  = tid & 15;
    const int ty  = tid >> 4;
    const int q0  = blockIdx.x * 64;

    {
        const int r  = tid >> 6;
        const int c4 = (tid & 63) * 4;
        #pragma unroll
        for (int it = 0; it < 16; ++it) {
            const int q = it * 4 + r;
            const float4 v = *reinterpret_cast<const float4*>(
                &z[(size_t)(q0 + q) * ND + c4]);
            const float vv[4] = {v.x, v.y, v.z, v.w};
            #pragma unroll
            for (int j = 0; j < 4; ++j) {
                const int d = c4 + j;
                const int s = 4 * ((d >> 2) & 7);
                z_t[d][q ^ s] = vv[j];
            }
        }
    }
    {
        const int lane16 = tid & 15;
        const int rgrp   = tid >> 4;
        #pragma unroll 4
        for (int it = 0; it < 64; ++it) {
            const int k = it * 16 + rgrp;
            double ssum = 0.0;
            #pragma unroll
            for (int h = 0; h < 4; ++h) {
                const float4 v = *reinterpret_cast<const float4*>(
                    &cb[(size_t)k * ND + lane16 * 16 + h * 4]);
                ssum += (double)v.x * v.x + (double)v.y * v.y
                      + (double)v.z * v.z + (double)v.w * v.w;
            }
            #pragma unroll
            for (int m = 8; m >= 1; m >>= 1) ssum += __shfl_xor(ssum, m);
            if (lane16 == 0) csq[k] = (float)ssum;
        }
    }

    double bestd[4]; int besti[4];
    #pragma unroll
    for (int i = 0; i < 4; ++i) { bestd[i] = 1e300; besti[i] = 0; }

    for (int kt = 0; kt < 16; ++kt) {
        double acc[4][4];
        #pragma unroll
        for (int i = 0; i < 4; ++i)
            #pragma unroll
            for (int j = 0; j < 4; ++j) acc[i][j] = 0.0;

        for (int dc = 0; dc < 8; ++dc) {
            __syncthreads();
            {
                const int kk = tid >> 3;
                const int dd = (tid & 7) * 4;
                #pragma unroll
                for (int h = 0; h < 2; ++h) {
                    const int k = kk + h * 32;
                    const float4 v = *reinterpret_cast<const float4*>(
                        &cb[(size_t)(kt * 64 + k) * ND + dc * 32 + dd]);
                    const float vv[4] = {v.x, v.y, v.z, v.w};
                    #pragma unroll
                    for (int j = 0; j < 4; ++j) {
                        const int d = dd + j;
                        const int s = 4 * ((d >> 2) & 7);
                        cb_t[d][k ^ s] = vv[j];
                    }
                }
            }
            __syncthreads();

            float cr[4][4];
            #pragma unroll
            for (int i = 0; i < 4; ++i)
                #pragma unroll
                for (int j = 0; j < 4; ++j) cr[i][j] = 0.0f;

            #pragma unroll 8
            for (int d = 0; d < 32; ++d) {
                const int s  = 4 * ((d >> 2) & 7);
                const int dg = dc * 32 + d;
                const float4 zv4 = *reinterpret_cast<const float4*>(
                    &z_t[dg][(4 * ty) ^ s]);
                const float4 cv4 = *reinterpret_cast<const float4*>(
                    &cb_t[d][(4 * tx) ^ s]);
                const float zv[4] = {zv4.x, zv4.y, zv4.z, zv4.w};
                const float cv[4] = {cv4.x, cv4.y, cv4.z, cv4.w};
                #pragma unroll
                for (int i = 0; i < 4; ++i)
                    #pragma unroll
                    for (int j = 0; j < 4; ++j)
                        cr[i][j] = fmaf(zv[i], cv[j], cr[i][j]);
            }
            #pragma unroll
            for (int i = 0; i < 4; ++i)
                #pragma unroll
                for (int j = 0; j < 4; ++j)
                    acc[i][j] += (double)cr[i][j];
        }

        #pragma unroll
        for (int j = 0; j < 4; ++j) {
            const int k = kt * 64 + tx * 4 + j;
            const double cs = (double)csq[k];
            #pragma unroll
            for (int i = 0; i < 4; ++i) {
                const double dist = cs - 2.0 * acc[i][j];
                if (dist < bestd[i]) { bestd[i] = dist; besti[i] = k; }
            }
        }
    }

    #pragma unroll
    for (int i = 0; i < 4; ++i) {
        double bd = bestd[i]; int bi = besti[i];
        #pragma unroll
        for (int m = 8; m >= 1; m >>= 1) {
            const double od = __shfl_xor(bd, m);
            const int    oi = __shfl_xor(bi, m);
            if (od < bd || (od == bd && oi < bi)) { bd = od; bi = oi; }
        }
        if (tx == 0) idx_lds[ty * 4 + i] = bi;
    }
    __syncthreads();

    {
        const int r = tid >> 6;
        const int c = (tid & 63) * 4;
        #pragma unroll
        for (int it = 0; it < 16; ++it) {
            const int q = it * 4 + r;
            const int k = idx_lds[q];
            const float4 v = *reinterpret_cast<const float4*>(
                &cb[(size_t)k * ND + c]);
            *reinterpret_cast<float4*>(&out[(size_t)(q0 + q) * ND + c]) = v;
        }
    }
}

extern "C" void kernel_launch(void* const* d_in, const int* in_sizes, int n_in,
                              void* d_out, int out_size, void* d_ws, size_t ws_size,
                              hipStream_t stream)
{
    const float* z   = (const float*)d_in[0];   // [B,T,D] fp32
    const float* cbk = (const float*)d_in[1];   // [K,D]  fp32
    float* out = (float*)d_out;
    uint8_t* ws = (uint8_t*)d_ws;

    if (ws_size < (size_t)WS_NEEDED) {
        vq_fallback<<<NQ / 64, 256, 0, stream>>>(z, cbk, out);
        return;
    }

    vq_prep<<<NK / 4, 256, 0, stream>>>(cbk, ws);
    vq_main<<<NQ / 64, 512, 0, stream>>>(z, cbk, ws, out);
}